// Round 7
// baseline (273.648 us; speedup 1.0000x reference)
//
#include <hip/hip_runtime.h>
#include <cstdint>
#include <cmath>

typedef __bf16 bf16_t;
typedef __attribute__((ext_vector_type(8))) __bf16 bf16x8;
typedef __attribute__((ext_vector_type(4))) __bf16 bf16x4;
typedef __attribute__((ext_vector_type(4))) float f32x4;

#define AS1 __attribute__((address_space(1)))
#define AS3 __attribute__((address_space(3)))

// ---------------------------------------------------------------------------
// PROVEN 128x128 NT bf16 GEMM body (BK=64, 256 thr, dbuf 64KB LDS, one
// barrier/iter, XOR-swizzled LDS, conflict-free). ~717-729 TF measured =
// this structure's ceiling (rounds 9/10/11 structure experiments all closed;
// round 12 SWAPXY killed the L2 over-fetch, FETCH 67.6->32.8MB, time flat ->
// NOT delivery-bound). Body is shared by all GEMM entry points below.
// ---------------------------------------------------------------------------
template <typename OutT>
__device__ __forceinline__
void gemm128_body(const bf16_t* A, const bf16_t* B, OutT* C,
                  int K, int lda, int ldb, int ldc, int m0, int n0,
                  bf16_t (*As)[128 * 64], bf16_t (*Bs)[128 * 64])
{
  const int tid = threadIdx.x;
  const int wave = tid >> 6, lane = tid & 63;
  const int lm = lane & 15, qd = lane >> 4;
  const int wm = (wave >> 1) * 64, wn = (wave & 1) * 64;

  const int rowl = lane >> 3;           // 0..7
  const int q = (lane & 7) ^ rowl;      // swizzled chunk within row
  const bf16_t* Abase = A + (long)(m0 + wave * 8 + rowl) * lda + q * 8;
  const bf16_t* Bbase = B + (long)(n0 + wave * 8 + rowl) * ldb + q * 8;
  const int woff = wave * 512;

  auto stage = [&](int k0, int b) {
#pragma unroll
    for (int i = 0; i < 4; i++) {
      __builtin_amdgcn_global_load_lds((const AS1 void*)(Abase + (long)i * 32 * lda + k0),
                                       (AS3 void*)(As[b] + woff + i * 2048), 16, 0, 0);
      __builtin_amdgcn_global_load_lds((const AS1 void*)(Bbase + (long)i * 32 * ldb + k0),
                                       (AS3 void*)(Bs[b] + woff + i * 2048), 16, 0, 0);
    }
  };

  f32x4 acc[4][4] = {};

  stage(0, 0);
  int buf = 0;
  for (int k0 = 0; k0 < K; k0 += 64) {
    __syncthreads();                   // drains tile-k loads (issued 1 iter ago)
    if (k0 + 64 < K) stage(k0 + 64, buf ^ 1);
#pragma unroll
    for (int s = 0; s < 2; s++) {
      bf16x8 aF[4], bF[4];
#pragma unroll
      for (int i = 0; i < 4; i++) {
        const int r = wm + i * 16 + lm;
        aF[i] = *(const bf16x8*)&As[buf][r * 64 + (((s * 4 + qd) ^ (lm & 7)) << 3)];
      }
#pragma unroll
      for (int j = 0; j < 4; j++) {
        const int r = wn + j * 16 + lm;
        bF[j] = *(const bf16x8*)&Bs[buf][r * 64 + (((s * 4 + qd) ^ (lm & 7)) << 3)];
      }
#pragma unroll
      for (int i = 0; i < 4; i++)
#pragma unroll
        for (int j = 0; j < 4; j++)
          acc[i][j] = __builtin_amdgcn_mfma_f32_16x16x32_bf16(aF[i], bF[j], acc[i][j], 0, 0, 0);
    }
    buf ^= 1;
  }

#pragma unroll
  for (int i = 0; i < 4; i++) {
    const int row = m0 + wm + i * 16 + qd * 4;
#pragma unroll
    for (int j = 0; j < 4; j++) {
      const int col = n0 + wn + j * 16 + lm;
#pragma unroll
      for (int r = 0; r < 4; r++)
        C[(long)(row + r) * ldc + col] = (OutT)acc[i][j][r];
    }
  }
}

// ---------------------------------------------------------------------------
// Fused steps 2+3 (round-13): ONE dispatch, 1536 blocks. Steps are
// independent, same 128^2 body, single code path after a block-uniform
// parameter select -> no per-operand register growth (round-8's failed merge
// duplicated accumulators inside the loop; this doesn't).
//   blocks [0,1024):    QK = Xb @ WT      (M=8192,N=2048,K=1024)
//       decode bm=id&63, bn=id>>6  -> id%8=bm%8: same-A-panel per XCD
//       (round-12 SWAPXY result: FETCH 67.6->32.8MB, keep it)
//   blocks [1024,1536): VT = WvT @ Xb^T   (M=1024,N=8192,K=1024)
//       decode bn=j&63, bm=j>>6    -> id%8=bn%8: big-B (Xb) panels per XCD
// s3's blocks backfill s2's dispatch tail (previously a serialized gap).
// ---------------------------------------------------------------------------
__global__ __launch_bounds__(256)
void gemm_qkv(const bf16_t* __restrict__ Xb, const bf16_t* __restrict__ WT,
              bf16_t* __restrict__ QK, bf16_t* __restrict__ VT)
{
  __shared__ bf16_t As[2][128 * 64];
  __shared__ bf16_t Bs[2][128 * 64];

  const int id = blockIdx.x;
  const bf16_t *Ap, *Bp;
  bf16_t* Cp;
  int bm, bn, ldc;
  if (id < 1024) {          // step 2
    bm = id & 63; bn = id >> 6;
    Ap = Xb; Bp = WT; Cp = QK; ldc = 2048;
  } else {                  // step 3
    const int j = id - 1024;
    bn = j & 63; bm = j >> 6;
    Ap = WT + (long)2048 * 1024; Bp = Xb; Cp = VT; ldc = 8192;
  }
  gemm128_body<bf16_t>(Ap, Bp, Cp, 1024, 1024, 1024, ldc,
                       bm * 128, bn * 128, As, Bs);
}

// ---------------------------------------------------------------------------
// Causal 128x128 NT GEMM. TRI=1 (step 4, S=QK^T): PACKED lower-triangle grid
// (136 jobs/batch, no dead blocks; round-13 — previously 1024 blocks with 480
// early-returns). TRI=0 (step 6, PV): grid (8,16,4), Keff=(bm+1)*128,
// heavy-first flip; matches softmax's 128-granular zero-fill.
// ---------------------------------------------------------------------------
template <typename OutT, int TAG, int TRI>
__global__ __launch_bounds__(256)
void gemm_ntc(const bf16_t* __restrict__ A, const bf16_t* __restrict__ B,
              OutT* __restrict__ C, int K, int lda, int ldb, int ldc,
              long sA, long sB, long sC, int kLimit)
{
  int bm, bn;
  if (TRI) {                 // unpack lower-triangle job id -> (bm, bn<=bm)
    const int j = blockIdx.x;
    bm = (int)((sqrtf(8.f * j + 1.f) - 1.f) * 0.5f);
    if (bm * (bm + 1) / 2 > j) bm--;       // defensive fp rounding guard
    bn = j - bm * (bm + 1) / 2;
  } else {
    bm = blockIdx.y;
    bn = blockIdx.x;
    if (kLimit) bm = gridDim.y - 1 - bm;   // heavy tiles dispatch first
  }
  const bf16_t* Ab = A + (long)blockIdx.z * sA;
  const bf16_t* Bb = B + (long)blockIdx.z * sB;
  OutT* Cb = C + (long)blockIdx.z * sC;
  int Keff = K;
  if (!TRI && kLimit) { const int kl = (bm + 1) * 128; if (kl < Keff) Keff = kl; }

  __shared__ bf16_t As[2][128 * 64];
  __shared__ bf16_t Bs[2][128 * 64];
  gemm128_body<OutT>(Ab, Bb, Cb, Keff, lda, ldb, ldc,
                     bm * 128, bn * 128, As, Bs);
}

// ---------------------------------------------------------------------------
// prep v2 (round-13): blocks [0,2048): grid-stride X fp32->bf16 (4 float4
// per thread; the old 8192-block one-float4-per-thread version was
// launch/latency-bound, not HBM-bound). blocks [2048,2048+3072): W
// transpose+convert, unchanged (32x32 LDS tiles).
// ---------------------------------------------------------------------------
__global__ __launch_bounds__(256)
void prep(const float* __restrict__ X, bf16_t* __restrict__ Xb,
          const float* __restrict__ wq, const float* __restrict__ wk,
          const float* __restrict__ wv, bf16_t* __restrict__ WT)
{
  const int b = blockIdx.x;
  if (b < 2048) {                       // X -> bf16, grid-stride, 4 f4/thread
    const int N4 = 8192 * 1024 / 4;     // 2,097,152 float4s
    const int stride = 2048 * 256;
    for (int i = b * 256 + threadIdx.x; i < N4; i += stride) {
      const float4 f = ((const float4*)X)[i];
      bf16x4 o = {(bf16_t)f.x, (bf16_t)f.y, (bf16_t)f.z, (bf16_t)f.w};
      ((bf16x4*)Xb)[i] = o;
    }
    return;
  }
  const int wid = b - 2048;             // 0..3071
  const int z = wid >> 10;              // which W
  const int t = wid & 1023;             // tile id, 32x32 grid of 32x32 tiles
  const int tix = t & 31, tiy = t >> 5;
  const float* W = (z == 0) ? wq : (z == 1) ? wk : wv;
  bf16_t* O = WT + (long)z * 1024 * 1024;

  __shared__ float tile[32][33];
  const int x = threadIdx.x & 31, y0 = threadIdx.x >> 5;
#pragma unroll
  for (int r = 0; r < 4; r++) {         // read: coalesced over out dim (x)
    const int y = y0 + r * 8;
    tile[y][x] = W[(long)(tiy * 32 + y) * 1024 + (tix * 32 + x)];
  }
  __syncthreads();
#pragma unroll
  for (int r = 0; r < 4; r++) {         // write: coalesced over in dim (x)
    const int y = y0 + r * 8;
    O[(long)(tix * 32 + y) * 1024 + (tiy * 32 + x)] = (bf16_t)tile[x][y];
  }
}

// ---------------------------------------------------------------------------
// In-place causal softmax over S rows (bf16, ld=2048). One block per row.
// logits = S/32; writes P = softmax, zeros above the diagonal.
// Loads only j <= t; stores only j < kend = ((t>>7)+1)*128 — beyond kend P
// is never read by the PV GEMM (Keff stops there); [t+1, kend) gets zeros.
// ---------------------------------------------------------------------------
__global__ __launch_bounds__(256)
void softmax_causal(bf16_t* __restrict__ S)
{
  const int row = blockIdx.x;
  const int t = row & 2047;
  const int kend = ((t >> 7) + 1) << 7;
  bf16_t* Sr = S + (long)row * 2048;
  const int base = threadIdx.x * 8;

  uint4 u = {0, 0, 0, 0};
  if (base <= t) u = *(const uint4*)(Sr + base);
  const unsigned short* up = (const unsigned short*)&u;
  float v[8];
  float m = -3.0e38f;
#pragma unroll
  for (int j = 0; j < 8; j++) {
    const float x = __uint_as_float(((unsigned)up[j]) << 16);  // bf16 -> f32
    v[j] = (base + j <= t) ? x : -3.0e38f;
    m = fmaxf(m, v[j]);
  }
#pragma unroll
  for (int off = 32; off > 0; off >>= 1) m = fmaxf(m, __shfl_xor(m, off));
  __shared__ float redm[4], redl[4];
  const int wave = threadIdx.x >> 6, lane = threadIdx.x & 63;
  if (lane == 0) redm[wave] = m;
  __syncthreads();
  m = fmaxf(fmaxf(redm[0], redm[1]), fmaxf(redm[2], redm[3]));

  float p[8], l = 0.f;
#pragma unroll
  for (int j = 0; j < 8; j++) {
    p[j] = (base + j <= t) ? __expf((v[j] - m) * 0.03125f) : 0.f;
    l += p[j];
  }
#pragma unroll
  for (int off = 32; off > 0; off >>= 1) l += __shfl_xor(l, off);
  if (lane == 0) redl[wave] = l;
  __syncthreads();
  l = (redl[0] + redl[1]) + (redl[2] + redl[3]);
  const float rl = 1.0f / l;

  if (base < kend) {
    uint4 w;
    unsigned* wp = (unsigned*)&w;
#pragma unroll
    for (int h = 0; h < 4; h++) {
      bf16_t a = (bf16_t)(p[2 * h] * rl);
      bf16_t b = (bf16_t)(p[2 * h + 1] * rl);
      wp[h] = (unsigned)__builtin_bit_cast(unsigned short, a) |
              ((unsigned)__builtin_bit_cast(unsigned short, b) << 16);
    }
    *(uint4*)(Sr + base) = w;
  }
}

// ---------------------------------------------------------------------------
extern "C" void kernel_launch(void* const* d_in, const int* in_sizes, int n_in,
                              void* d_out, int out_size, void* d_ws, size_t ws_size,
                              hipStream_t stream)
{
  const float* X  = (const float*)d_in[0];  // [4,2048,1024]
  const float* Wq = (const float*)d_in[1];  // [1024,1024] (in,out)
  const float* Wk = (const float*)d_in[2];
  const float* Wv = (const float*)d_in[3];
  float* out = (float*)d_out;               // [4,2048,1024]

  // workspace layout (bytes): QK 33.5M | VT 16.8M | WT 6.3M | {Xb 16.8M / S 33.5M overlap}
  char* p = (char*)d_ws;
  bf16_t* QK = (bf16_t*)p;  p += (size_t)8192 * 2048 * 2;   // [8192, 2048]  Q|K
  bf16_t* VT = (bf16_t*)p;  p += (size_t)1024 * 8192 * 2;   // [1024, 8192]  V^T
  bf16_t* WT = (bf16_t*)p;  p += (size_t)3072 * 1024 * 2;   // [3072, 1024]  Wq^T|Wk^T|Wv^T
  bf16_t* Xb = (bf16_t*)p;                                  // [8192, 1024]  (dead before S)
  bf16_t* S  = (bf16_t*)p;                                  // [4][2048,2048] scores->P

  // 1) prep v2: X -> bf16 (grid-stride) + W -> WT (transposed)
  prep<<<2048 + 3072, 256, 0, stream>>>(X, Xb, Wq, Wk, Wv, WT);
  // 2+3) fused: QK = Xb @ [Wq|Wk]  AND  VT = WvT @ Xb^T   (1536 blocks)
  gemm_qkv<<<1536, 256, 0, stream>>>(Xb, WT, QK, VT);
  // 4) S = Q @ K^T per batch, packed lower-tri grid (136 jobs x 4 batches)
  gemm_ntc<bf16_t, 4, 1><<<dim3(136, 1, 4), 256, 0, stream>>>(
      QK, QK + 1024, S, 1024, 2048, 2048, 2048,
      (long)2048 * 2048, (long)2048 * 2048, (long)2048 * 2048, 0);
  // 5) in-place causal softmax (128-granular truncated IO)
  softmax_causal<<<8192, 256, 0, stream>>>(S);
  // 6) O = P @ V (NT vs V^T), 128-row tiles, Keff=(bm+1)*128, heavy-first
  gemm_ntc<float, 6, 0><<<dim3(8, 16, 4), 256, 0, stream>>>(
      S, VT, out, 2048, 2048, 8192, 1024,
      (long)2048 * 2048, 2048, (long)2048 * 1024, 1);
}

// Round 8
// 247.524 us; speedup vs baseline: 1.1055x; 1.1055x over previous
//
#include <hip/hip_runtime.h>
#include <cstdint>
#include <cmath>

typedef __bf16 bf16_t;
typedef __attribute__((ext_vector_type(8))) __bf16 bf16x8;
typedef __attribute__((ext_vector_type(4))) __bf16 bf16x4;
typedef __attribute__((ext_vector_type(4))) float f32x4;

#define AS1 __attribute__((address_space(1)))
#define AS3 __attribute__((address_space(3)))

// ---------------------------------------------------------------------------
// Big-tile NT bf16 GEMM: C[m,n] = sum_k A[m*lda+k] * B[n*ldb+k]
// Tile 128x128, BK=64, 256 threads, DOUBLE-BUFFERED LDS (64KB, 2 blocks/CU).
// One barrier/iter. 717-729 TF measured = this structure's ceiling.
// STANDALONE KERNEL, VERBATIM round-6 body. DO NOT merge operand sets into
// one kernel (round-8 AND round-13 both measured: VGPR 88->132, -33-50%).
// Structure lane closed (rounds 9/10/11); delivery lane closed (round 12:
// SWAPXY fixed FETCH 67.6->32.8MB, time flat).
//
// TAG: unique mangled symbol per pipeline step for rocprof attribution.
// SWAPXY=1: grid (x=bm, y=bn) -> id%8=bm%8 -> same-A-panel blocks per XCD
// (per-XCD A working set 2MB fits L2; round-12 verified on traffic).
//
// LDS layout: rows of 8 16B-chunks, chunk q of row r at slot q ^ (r&7)
// (XOR swizzle): conflict-free ds_read_b128 (measured 0 conflicts).
// ---------------------------------------------------------------------------
template <typename OutT, int TAG, int SWAPXY>
__global__ __launch_bounds__(256)
void gemm_nt(const bf16_t* __restrict__ A, const bf16_t* __restrict__ B,
             OutT* __restrict__ C, int K, int lda, int ldb, int ldc)
{
  const int bm = SWAPXY ? blockIdx.x : blockIdx.y;
  const int bn = SWAPXY ? blockIdx.y : blockIdx.x;
  const int m0 = bm * 128, n0 = bn * 128;

  __shared__ bf16_t As[2][128 * 64];  // 16KB each
  __shared__ bf16_t Bs[2][128 * 64];

  const int tid = threadIdx.x;
  const int wave = tid >> 6, lane = tid & 63;
  const int lm = lane & 15, qd = lane >> 4;
  const int wm = (wave >> 1) * 64, wn = (wave & 1) * 64;

  const int rowl = lane >> 3;           // 0..7
  const int q = (lane & 7) ^ rowl;      // swizzled chunk within row
  const bf16_t* Abase = A + (long)(m0 + wave * 8 + rowl) * lda + q * 8;
  const bf16_t* Bbase = B + (long)(n0 + wave * 8 + rowl) * ldb + q * 8;
  const int woff = wave * 512;

  auto stage = [&](int k0, int b) {
#pragma unroll
    for (int i = 0; i < 4; i++) {
      __builtin_amdgcn_global_load_lds((const AS1 void*)(Abase + (long)i * 32 * lda + k0),
                                       (AS3 void*)(As[b] + woff + i * 2048), 16, 0, 0);
      __builtin_amdgcn_global_load_lds((const AS1 void*)(Bbase + (long)i * 32 * ldb + k0),
                                       (AS3 void*)(Bs[b] + woff + i * 2048), 16, 0, 0);
    }
  };

  f32x4 acc[4][4] = {};

  stage(0, 0);
  int buf = 0;
  for (int k0 = 0; k0 < K; k0 += 64) {
    __syncthreads();                   // drains tile-k loads (issued 1 iter ago)
    if (k0 + 64 < K) stage(k0 + 64, buf ^ 1);
#pragma unroll
    for (int s = 0; s < 2; s++) {
      bf16x8 aF[4], bF[4];
#pragma unroll
      for (int i = 0; i < 4; i++) {
        const int r = wm + i * 16 + lm;
        aF[i] = *(const bf16x8*)&As[buf][r * 64 + (((s * 4 + qd) ^ (lm & 7)) << 3)];
      }
#pragma unroll
      for (int j = 0; j < 4; j++) {
        const int r = wn + j * 16 + lm;
        bF[j] = *(const bf16x8*)&Bs[buf][r * 64 + (((s * 4 + qd) ^ (lm & 7)) << 3)];
      }
#pragma unroll
      for (int i = 0; i < 4; i++)
#pragma unroll
        for (int j = 0; j < 4; j++)
          acc[i][j] = __builtin_amdgcn_mfma_f32_16x16x32_bf16(aF[i], bF[j], acc[i][j], 0, 0, 0);
    }
    buf ^= 1;
  }

#pragma unroll
  for (int i = 0; i < 4; i++) {
    const int row = m0 + wm + i * 16 + qd * 4;
#pragma unroll
    for (int j = 0; j < 4; j++) {
      const int col = n0 + wn + j * 16 + lm;
#pragma unroll
      for (int r = 0; r < 4; r++)
        C[(long)(row + r) * ldc + col] = (OutT)acc[i][j][r];
    }
  }
}

// ---------------------------------------------------------------------------
// Causal 128x128 NT GEMM — verbatim gemm_nt body + batch strides + causal
// block-mapping modes.
//
// TRI=1 (step 4, S=QK^T): PACKED lower-triangle grid (136 jobs/batch, no
//   dead blocks), closed-form (bm, bn<=bm) unpack.
// TRI=0 (step 6, PV): grid (8,16,4), Keff=(bm+1)*128.
//   ROUND-14 PAIRING FIX: per-block work spans 4.2..67 MF with Keff. Blocks
//   i and i+256 share (x,y), differ in z(0<->2,1<->3); under breadth-first
//   round-robin block->CU assignment they CO-LOCATE on a CU. Old heavy-first
//   (all z) paired bm=15 with bm=15 -> CU load 2x67MF -> 48us makespan while
//   light CUs idle. Now: z<2 heavy-first (bm=15-y), z>=2 light-first (bm=y)
//   -> per-CU Keff sum = (16-y+y+1)*128 = 2176 CONSTANT -> ~25us makespan.
// ---------------------------------------------------------------------------
template <typename OutT, int TAG, int TRI>
__global__ __launch_bounds__(256)
void gemm_ntc(const bf16_t* __restrict__ A, const bf16_t* __restrict__ B,
              OutT* __restrict__ C, int K, int lda, int ldb, int ldc,
              long sA, long sB, long sC, int kLimit)
{
  int bm, bn;
  if (TRI) {                 // unpack lower-triangle job id -> (bm, bn<=bm)
    const int j = blockIdx.x;
    bm = (int)((sqrtf(8.f * j + 1.f) - 1.f) * 0.5f);
    while ((bm + 1) * (bm + 2) / 2 <= j) bm++;   // fp rounding guards
    while (bm * (bm + 1) / 2 > j) bm--;
    bn = j - bm * (bm + 1) / 2;
  } else {
    bn = blockIdx.x;
    bm = blockIdx.y;
    if (kLimit) bm = (blockIdx.z & 2) ? bm : (gridDim.y - 1 - bm);
  }
  A += (long)blockIdx.z * sA;
  B += (long)blockIdx.z * sB;
  C += (long)blockIdx.z * sC;
  const int m0 = bm * 128, n0 = bn * 128;
  int Keff = K;
  if (!TRI && kLimit) { const int kl = (bm + 1) * 128; if (kl < Keff) Keff = kl; }

  __shared__ bf16_t As[2][128 * 64];  // 16KB each
  __shared__ bf16_t Bs[2][128 * 64];

  const int tid = threadIdx.x;
  const int wave = tid >> 6, lane = tid & 63;
  const int lm = lane & 15, qd = lane >> 4;
  const int wm = (wave >> 1) * 64, wn = (wave & 1) * 64;

  const int rowl = lane >> 3;           // 0..7
  const int q = (lane & 7) ^ rowl;      // swizzled chunk within row
  const bf16_t* Abase = A + (long)(m0 + wave * 8 + rowl) * lda + q * 8;
  const bf16_t* Bbase = B + (long)(n0 + wave * 8 + rowl) * ldb + q * 8;
  const int woff = wave * 512;

  auto stage = [&](int k0, int b) {
#pragma unroll
    for (int i = 0; i < 4; i++) {
      __builtin_amdgcn_global_load_lds((const AS1 void*)(Abase + (long)i * 32 * lda + k0),
                                       (AS3 void*)(As[b] + woff + i * 2048), 16, 0, 0);
      __builtin_amdgcn_global_load_lds((const AS1 void*)(Bbase + (long)i * 32 * ldb + k0),
                                       (AS3 void*)(Bs[b] + woff + i * 2048), 16, 0, 0);
    }
  };

  f32x4 acc[4][4] = {};

  stage(0, 0);
  int buf = 0;
  for (int k0 = 0; k0 < Keff; k0 += 64) {
    __syncthreads();                   // drains tile-k loads (issued 1 iter ago)
    if (k0 + 64 < Keff) stage(k0 + 64, buf ^ 1);
#pragma unroll
    for (int s = 0; s < 2; s++) {
      bf16x8 aF[4], bF[4];
#pragma unroll
      for (int i = 0; i < 4; i++) {
        const int r = wm + i * 16 + lm;
        aF[i] = *(const bf16x8*)&As[buf][r * 64 + (((s * 4 + qd) ^ (lm & 7)) << 3)];
      }
#pragma unroll
      for (int j = 0; j < 4; j++) {
        const int r = wn + j * 16 + lm;
        bF[j] = *(const bf16x8*)&Bs[buf][r * 64 + (((s * 4 + qd) ^ (lm & 7)) << 3)];
      }
#pragma unroll
      for (int i = 0; i < 4; i++)
#pragma unroll
        for (int j = 0; j < 4; j++)
          acc[i][j] = __builtin_amdgcn_mfma_f32_16x16x32_bf16(aF[i], bF[j], acc[i][j], 0, 0, 0);
    }
    buf ^= 1;
  }

#pragma unroll
  for (int i = 0; i < 4; i++) {
    const int row = m0 + wm + i * 16 + qd * 4;
#pragma unroll
    for (int j = 0; j < 4; j++) {
      const int col = n0 + wn + j * 16 + lm;
#pragma unroll
      for (int r = 0; r < 4; r++)
        C[(long)(row + r) * ldc + col] = (OutT)acc[i][j][r];
    }
  }
}

// ---------------------------------------------------------------------------
// prep v2: blocks [0,2048): grid-stride X fp32->bf16 (4 float4/thread);
// blocks [2048,2048+3072): W transpose+convert (32x32 LDS tiles).
// ---------------------------------------------------------------------------
__global__ __launch_bounds__(256)
void prep(const float* __restrict__ X, bf16_t* __restrict__ Xb,
          const float* __restrict__ wq, const float* __restrict__ wk,
          const float* __restrict__ wv, bf16_t* __restrict__ WT)
{
  const int b = blockIdx.x;
  if (b < 2048) {                       // X -> bf16, grid-stride, 4 f4/thread
    const int N4 = 8192 * 1024 / 4;     // 2,097,152 float4s
    const int stride = 2048 * 256;
    for (int i = b * 256 + threadIdx.x; i < N4; i += stride) {
      const float4 f = ((const float4*)X)[i];
      bf16x4 o = {(bf16_t)f.x, (bf16_t)f.y, (bf16_t)f.z, (bf16_t)f.w};
      ((bf16x4*)Xb)[i] = o;
    }
    return;
  }
  const int wid = b - 2048;             // 0..3071
  const int z = wid >> 10;              // which W
  const int t = wid & 1023;             // tile id, 32x32 grid of 32x32 tiles
  const int tix = t & 31, tiy = t >> 5;
  const float* W = (z == 0) ? wq : (z == 1) ? wk : wv;
  bf16_t* O = WT + (long)z * 1024 * 1024;

  __shared__ float tile[32][33];
  const int x = threadIdx.x & 31, y0 = threadIdx.x >> 5;
#pragma unroll
  for (int r = 0; r < 4; r++) {         // read: coalesced over out dim (x)
    const int y = y0 + r * 8;
    tile[y][x] = W[(long)(tiy * 32 + y) * 1024 + (tix * 32 + x)];
  }
  __syncthreads();
#pragma unroll
  for (int r = 0; r < 4; r++) {         // write: coalesced over in dim (x)
    const int y = y0 + r * 8;
    O[(long)(tix * 32 + y) * 1024 + (tiy * 32 + x)] = (bf16_t)tile[x][y];
  }
}

// ---------------------------------------------------------------------------
// In-place causal softmax over S rows (bf16, ld=2048). One block per row.
// logits = S/32; writes P = softmax, zeros above the diagonal.
// Loads only j <= t; stores only j < kend = ((t>>7)+1)*128 — beyond kend P
// is never read by the PV GEMM (Keff stops there); [t+1, kend) gets zeros.
// ---------------------------------------------------------------------------
__global__ __launch_bounds__(256)
void softmax_causal(bf16_t* __restrict__ S)
{
  const int row = blockIdx.x;
  const int t = row & 2047;
  const int kend = ((t >> 7) + 1) << 7;
  bf16_t* Sr = S + (long)row * 2048;
  const int base = threadIdx.x * 8;

  uint4 u = {0, 0, 0, 0};
  if (base <= t) u = *(const uint4*)(Sr + base);
  const unsigned short* up = (const unsigned short*)&u;
  float v[8];
  float m = -3.0e38f;
#pragma unroll
  for (int j = 0; j < 8; j++) {
    const float x = __uint_as_float(((unsigned)up[j]) << 16);  // bf16 -> f32
    v[j] = (base + j <= t) ? x : -3.0e38f;
    m = fmaxf(m, v[j]);
  }
#pragma unroll
  for (int off = 32; off > 0; off >>= 1) m = fmaxf(m, __shfl_xor(m, off));
  __shared__ float redm[4], redl[4];
  const int wave = threadIdx.x >> 6, lane = threadIdx.x & 63;
  if (lane == 0) redm[wave] = m;
  __syncthreads();
  m = fmaxf(fmaxf(redm[0], redm[1]), fmaxf(redm[2], redm[3]));

  float p[8], l = 0.f;
#pragma unroll
  for (int j = 0; j < 8; j++) {
    p[j] = (base + j <= t) ? __expf((v[j] - m) * 0.03125f) : 0.f;
    l += p[j];
  }
#pragma unroll
  for (int off = 32; off > 0; off >>= 1) l += __shfl_xor(l, off);
  if (lane == 0) redl[wave] = l;
  __syncthreads();
  l = (redl[0] + redl[1]) + (redl[2] + redl[3]);
  const float rl = 1.0f / l;

  if (base < kend) {
    uint4 w;
    unsigned* wp = (unsigned*)&w;
#pragma unroll
    for (int h = 0; h < 4; h++) {
      bf16_t a = (bf16_t)(p[2 * h] * rl);
      bf16_t b = (bf16_t)(p[2 * h + 1] * rl);
      wp[h] = (unsigned)__builtin_bit_cast(unsigned short, a) |
              ((unsigned)__builtin_bit_cast(unsigned short, b) << 16);
    }
    *(uint4*)(Sr + base) = w;
  }
}

// ---------------------------------------------------------------------------
extern "C" void kernel_launch(void* const* d_in, const int* in_sizes, int n_in,
                              void* d_out, int out_size, void* d_ws, size_t ws_size,
                              hipStream_t stream)
{
  const float* X  = (const float*)d_in[0];  // [4,2048,1024]
  const float* Wq = (const float*)d_in[1];  // [1024,1024] (in,out)
  const float* Wk = (const float*)d_in[2];
  const float* Wv = (const float*)d_in[3];
  float* out = (float*)d_out;               // [4,2048,1024]

  // workspace layout (bytes): QK 33.5M | VT 16.8M | WT 6.3M | {Xb 16.8M / S 33.5M overlap}
  char* p = (char*)d_ws;
  bf16_t* QK = (bf16_t*)p;  p += (size_t)8192 * 2048 * 2;   // [8192, 2048]  Q|K
  bf16_t* VT = (bf16_t*)p;  p += (size_t)1024 * 8192 * 2;   // [1024, 8192]  V^T
  bf16_t* WT = (bf16_t*)p;  p += (size_t)3072 * 1024 * 2;   // [3072, 1024]  Wq^T|Wk^T|Wv^T
  bf16_t* Xb = (bf16_t*)p;                                  // [8192, 1024]  (dead before S)
  bf16_t* S  = (bf16_t*)p;                                  // [4][2048,2048] scores->P

  // 1) prep v2: X -> bf16 (grid-stride) + W -> WT (transposed)
  prep<<<2048 + 3072, 256, 0, stream>>>(X, Xb, Wq, Wk, Wv, WT);
  // 2) QK = Xb @ [Wq|Wk]   M=8192 N=2048 K=1024   (1024 blocks, SWAPXY)
  gemm_nt<bf16_t, 2, 1><<<dim3(64, 16), 256, 0, stream>>>(
      Xb, WT, QK, 1024, 1024, 1024, 2048);
  // 3) VT = WvT @ Xb^T     M=1024 N=8192 K=1024   (512 blocks)
  gemm_nt<bf16_t, 3, 0><<<dim3(64, 8), 256, 0, stream>>>(
      WT + (long)2048 * 1024, Xb, VT, 1024, 1024, 1024, 8192);
  // 4) S = Q @ K^T per batch, packed lower-tri grid (136 jobs x 4 batches)
  gemm_ntc<bf16_t, 4, 1><<<dim3(136, 1, 4), 256, 0, stream>>>(
      QK, QK + 1024, S, 1024, 2048, 2048, 2048,
      (long)2048 * 2048, (long)2048 * 2048, (long)2048 * 2048, 0);
  // 5) in-place causal softmax (128-granular truncated IO)
  softmax_causal<<<8192, 256, 0, stream>>>(S);
  // 6) O = P @ V (NT vs V^T), Keff=(bm+1)*128, z-paired heavy/light ordering
  gemm_ntc<float, 6, 0><<<dim3(8, 16, 4), 256, 0, stream>>>(
      S, VT, out, 2048, 2048, 8192, 1024,
      (long)2048 * 2048, 2048, (long)2048 * 1024, 1);
}